// Round 3
// baseline (208.857 us; speedup 1.0000x reference)
//
#include <hip/hip_runtime.h>
#include <hip/hip_bf16.h>
#include <stdint.h>

#define K_DIM 4096
#define N_DIM 8192
#define NTILES (N_DIM / 128)          // 64 B-row tiles
// flags: 512 ushort half-words. halfword h = ntile*8 + kh covers kchunks
// kh*16..kh*16+15 (cols kh*512..+511) of rows ntile*128..+127.
// Little-endian pairs make (uint4*)flags[ntile] == the 4 uint words
// {kchunk 0..31, 32..63, 64..95, 96..127} used by the gemm.
#define FLAG_HALFWORDS 512

typedef __attribute__((ext_vector_type(8))) __bf16 bf16x8;
typedef __attribute__((ext_vector_type(8))) unsigned short u16x8;
typedef __attribute__((ext_vector_type(4))) float f32x4;

// ---------- quantization: nearest of {0,±1,±.5,±.333333,±.2,±.142857,±.090909,±.076923} ----------
// Tie-break matches the reference's first-min LUT scan:
//   boundary to 0 (index 0 first) -> strict >; between nonzero magnitudes -> >=
__device__ __forceinline__ float quantize_ws(float ws, float scale) {
    float a  = fabsf(ws);
    float v  = 0.0f;
    v = (a >  0.0384615f) ? 0.076923f : v;
    v = (a >= 0.0839160f) ? 0.090909f : v;
    v = (a >= 0.1168830f) ? 0.142857f : v;
    v = (a >= 0.1714285f) ? 0.2f      : v;
    v = (a >= 0.2666665f) ? 0.333333f : v;
    v = (a >= 0.4166665f) ? 0.5f      : v;
    v = (a >= 0.75f)      ? 1.0f      : v;
    v = copysignf(v, ws);
    return v * scale;
}

__device__ __forceinline__ unsigned short to_bf16(float f) {
    unsigned int u = __float_as_uint(f);
    u += 0x7FFFu + ((u >> 16) & 1u);   // RNE
    return (unsigned short)(u >> 16);
}

// ---------- pass 1: scan W -> flags (no atomics/memset) + zero-fill C ----------
// Duty A (blocks sb < 512): compute flag halfword sb by scanning a 128x512
// region of W (256 KiB); wave-OR + LDS-OR reduce; single ushort store.
// Duty B (every block): zero-fill own 128x128 C tile (float4).
// Read (128 MiB) and write (32 MiB) streams overlap in one dispatch.
__global__ __launch_bounds__(256) void scan_fill_kernel(
        const float* __restrict__ W,
        const float* __restrict__ scale_p,
        unsigned short* __restrict__ flags_h,
        float* __restrict__ C, int M) {
    __shared__ unsigned int red[4];
    const int tid = threadIdx.x;
    const int b   = blockIdx.x;
    const int nwg = gridDim.x;
    const float th = 0.0384615f * fabsf(scale_p[0]);
    const float4* W4 = (const float4*)W;

    // --- duty A: flag halfwords (grid-stride so any grid >= 1 covers all 512) ---
    for (int sb = b; sb < FLAG_HALFWORDS; sb += nwg) {
        int ntile = sb >> 3;           // W row tile (N dim)
        int kh    = sb & 7;            // col half-word
        unsigned int mask = 0u;
        // 128 rows x 128 float4; consecutive tid -> consecutive float4 (coalesced)
#pragma unroll 4
        for (int e = tid; e < 128 * 128; e += 256) {
            int row = e >> 7;
            int c4  = e & 127;
            float4 w = W4[(size_t)(ntile * 128 + row) * (K_DIM / 4) + kh * 128 + c4];
            float amax = fmaxf(fmaxf(fabsf(w.x), fabsf(w.y)), fmaxf(fabsf(w.z), fabsf(w.w)));
            if (amax > th) mask |= 1u << (c4 >> 3);    // sub-kchunk 0..15
        }
#pragma unroll
        for (int off = 32; off; off >>= 1) mask |= __shfl_down(mask, off, 64);
        if ((tid & 63) == 0) red[tid >> 6] = mask;
        __syncthreads();
        if (tid == 0)
            flags_h[sb] = (unsigned short)(red[0] | red[1] | red[2] | red[3]);
        __syncthreads();               // red[] reuse safety when grid-striding
    }

    // --- duty B: zero own C tile ---
    int mtile = b >> 6;                // grid = (M/128) * 64
    int ntile = b & 63;
    const float4 zz = {0.f, 0.f, 0.f, 0.f};
    float4* C4 = (float4*)(C + (size_t)mtile * 128 * N_DIM + ntile * 128);
#pragma unroll 4
    for (int g = tid; g < 128 * 32; g += 256) {        // 128 rows x 32 float4
        int r = g >> 5, c = g & 31;
        C4[(size_t)r * (N_DIM / 4) + c] = zz;
    }
}

// ---------- pass 2: sparse-aware GEMM, C = x @ quant(W)^T, staging from fp32 ----------
// 128x128 tile, BK=32, 2x2 waves, 4x4 frags, 64 B LDS rows. Per-block early
// exit: all 4 flag words zero -> return (C tile already zeroed by pass 1).
// Nonzero chunks: stage A from fp32 x (bf16-convert) and B from fp32 W
// (quantize+convert) on the fly. Skipping a zero chunk is BIT-EXACT: every
// skipped term is acc += a*0, and x+0.0 == x.
__global__ __launch_bounds__(256) void gemm_bt_bf16(
        const float* __restrict__ X,            // [M][K] fp32
        const float* __restrict__ Wf,           // [N][K] fp32
        const float* __restrict__ scale_p,
        const unsigned int* __restrict__ flags, // uint view of flags_h
        float* __restrict__ C, int M) {
    __shared__ unsigned short sA[128 * 32];     // row-major [m][k], 64 B rows
    __shared__ unsigned short sB[128 * 32];

    const int tid  = threadIdx.x;
    const int ntile = blockIdx.x & 63;          // N/128 = 64
    const int mtile = blockIdx.x >> 6;
    const int m0 = mtile * 128;
    const int n0 = ntile * 128;

    const uint4 fw = ((const uint4*)flags)[ntile];
    const unsigned int f0 = fw.x, f1 = fw.y, f2 = fw.z, f3 = fw.w;

    if ((f0 | f1 | f2 | f3) == 0u) return;      // C tile already zero-filled

    const float s   = scale_p[0];
    const float inv = 1.0f / s;

    const int w    = tid >> 6;
    const int lane = tid & 63;
    const int quad = lane >> 4;
    const int l16  = lane & 15;
    const int wm   = w >> 1;                    // 2x2 wave grid
    const int wn   = w & 1;

    f32x4 acc[4][4];
    const f32x4 z = {0.f, 0.f, 0.f, 0.f};
#pragma unroll
    for (int i = 0; i < 4; ++i)
#pragma unroll
        for (int j = 0; j < 4; ++j) acc[i][j] = z;

    char* sAb = (char*)sA;
    char* sBb = (char*)sB;

    for (int k0 = 0; k0 < K_DIM; k0 += 32) {
        int ch = k0 >> 5;
        unsigned int word = (ch < 64) ? ((ch < 32) ? f0 : f1)
                                      : ((ch < 96) ? f2 : f3);
        if (!((word >> (ch & 31)) & 1u)) continue;   // block-uniform skip

        // stage 128x32: 512 groups of 8 elems; group g -> row g>>2, seg g&3.
        // Lanes 0..3 cover one row's 128 B contiguous fp32 -> coalesced.
#pragma unroll
        for (int p = 0; p < 2; ++p) {
            int g   = p * 256 + tid;
            int row = g >> 2;
            int seg = g & 3;
            const float* xa = X  + (size_t)(m0 + row) * K_DIM + k0 + seg * 8;
            const float* wb = Wf + (size_t)(n0 + row) * K_DIM + k0 + seg * 8;
            float4 a0 = *(const float4*)xa;
            float4 a1 = *(const float4*)(xa + 4);
            float4 b0 = *(const float4*)wb;
            float4 b1 = *(const float4*)(wb + 4);
            u16x8 qa, qb;
            qa[0] = to_bf16(a0.x); qa[1] = to_bf16(a0.y);
            qa[2] = to_bf16(a0.z); qa[3] = to_bf16(a0.w);
            qa[4] = to_bf16(a1.x); qa[5] = to_bf16(a1.y);
            qa[6] = to_bf16(a1.z); qa[7] = to_bf16(a1.w);
            qb[0] = to_bf16(quantize_ws(b0.x * inv, s));
            qb[1] = to_bf16(quantize_ws(b0.y * inv, s));
            qb[2] = to_bf16(quantize_ws(b0.z * inv, s));
            qb[3] = to_bf16(quantize_ws(b0.w * inv, s));
            qb[4] = to_bf16(quantize_ws(b1.x * inv, s));
            qb[5] = to_bf16(quantize_ws(b1.y * inv, s));
            qb[6] = to_bf16(quantize_ws(b1.z * inv, s));
            qb[7] = to_bf16(quantize_ws(b1.w * inv, s));
            *(u16x8*)(sAb + row * 64 + seg * 16) = qa;
            *(u16x8*)(sBb + row * 64 + seg * 16) = qb;
        }
        __syncthreads();

        bf16x8 af[4], bf[4];
#pragma unroll
        for (int i = 0; i < 4; ++i) {
            af[i] = *(const bf16x8*)(sAb + ((size_t)(wm * 64 + i * 16 + l16) * 32 + quad * 8) * 2);
            bf[i] = *(const bf16x8*)(sBb + ((size_t)(wn * 64 + i * 16 + l16) * 32 + quad * 8) * 2);
        }
#pragma unroll
        for (int mi = 0; mi < 4; ++mi)
#pragma unroll
            for (int ni = 0; ni < 4; ++ni)
                acc[mi][ni] = __builtin_amdgcn_mfma_f32_16x16x32_bf16(af[mi], bf[ni], acc[mi][ni], 0, 0, 0);
        __syncthreads();
    }

    // epilogue: D row = m (quad*4+reg), col = n (lane&15)  [verified mapping, m89/m91]
#pragma unroll
    for (int mi = 0; mi < 4; ++mi) {
#pragma unroll
        for (int ni = 0; ni < 4; ++ni) {
            int row = m0 + wm * 64 + mi * 16 + quad * 4;
            int col = n0 + wn * 64 + ni * 16 + l16;
#pragma unroll
            for (int r = 0; r < 4; ++r)
                C[(size_t)(row + r) * N_DIM + col] = acc[mi][ni][r];
        }
    }
}

// ---------- fallback (no usable workspace / odd M): fp32 tiled GEMM, quantize in staging ----------
__global__ __launch_bounds__(256) void gemm_fp32_fb(const float* __restrict__ A,
                                                    const float* __restrict__ B,
                                                    const float* __restrict__ scale_p,
                                                    float* __restrict__ C, int M) {
    __shared__ float sA[64][17];
    __shared__ float sB[64][17];
    const float s   = scale_p[0];
    const float inv = 1.0f / s;
    int tid = threadIdx.x;
    int tx = tid & 15, ty = tid >> 4;
    int n0 = (blockIdx.x & 127) * 64;          // N/64 = 128
    int m0 = (blockIdx.x >> 7) * 64;
    float acc[4][4] = {};
    for (int k0 = 0; k0 < K_DIM; k0 += 16) {
#pragma unroll
        for (int i = 0; i < 4; ++i) {
            int e = tid + i * 256;
            int r = e >> 4, c = e & 15;
            sA[r][c] = A[(size_t)(m0 + r) * K_DIM + k0 + c];
            sB[r][c] = quantize_ws(B[(size_t)(n0 + r) * K_DIM + k0 + c] * inv, s);
        }
        __syncthreads();
#pragma unroll
        for (int kk = 0; kk < 16; ++kk) {
            float a[4], b[4];
#pragma unroll
            for (int i = 0; i < 4; ++i) { a[i] = sA[ty * 4 + i][kk]; b[i] = sB[tx * 4 + i][kk]; }
#pragma unroll
            for (int i = 0; i < 4; ++i)
#pragma unroll
                for (int j = 0; j < 4; ++j) acc[i][j] += a[i] * b[j];
        }
        __syncthreads();
    }
#pragma unroll
    for (int i = 0; i < 4; ++i)
#pragma unroll
        for (int j = 0; j < 4; ++j)
            C[(size_t)(m0 + ty * 4 + i) * N_DIM + n0 + tx * 4 + j] = acc[i][j];
}

extern "C" void kernel_launch(void* const* d_in, const int* in_sizes, int n_in,
                              void* d_out, int out_size, void* d_ws, size_t ws_size,
                              hipStream_t stream) {
    const float* x     = (const float*)d_in[0];
    const float* W     = (const float*)d_in[1];
    const float* scale = (const float*)d_in[2];
    float* out = (float*)d_out;

    const int M = in_sizes[0] / K_DIM;                       // 1024
    const size_t fl_bytes = (size_t)FLAG_HALFWORDS * sizeof(unsigned short);  // 1024 B

    if (ws_size >= fl_bytes && (M % 128) == 0) {
        unsigned short* flags_h = (unsigned short*)d_ws;
        hipLaunchKernelGGL(scan_fill_kernel, dim3((M / 128) * NTILES), dim3(256), 0, stream,
                           W, scale, flags_h, out, M);
        hipLaunchKernelGGL(gemm_bt_bf16, dim3((M / 128) * NTILES), dim3(256), 0, stream,
                           x, W, scale, (const unsigned int*)flags_h, out, M);
    } else {
        hipLaunchKernelGGL(gemm_fp32_fb, dim3((M / 64) * (N_DIM / 64)), dim3(256), 0, stream,
                           x, W, scale, out, M);
    }
}

// Round 4
// 202.916 us; speedup vs baseline: 1.0293x; 1.0293x over previous
//
#include <hip/hip_runtime.h>
#include <hip/hip_bf16.h>
#include <stdint.h>

#define K_DIM 4096
#define N_DIM 8192
#define NTILES (N_DIM / 128)          // 64 B-row tiles
// flags: 4 partial arrays of 512 ushort half-words (one per 32-row quarter).
// halfword h = ntile*8 + kh covers kchunks kh*16..+15 (cols kh*512..+511) of
// rows ntile*128..+127 (partial p: rows ntile*128+p*32..+31). Little-endian
// pairs make (uint4*)partial_p[ntile] == the 4 uint words {kchunk 0..31,
// 32..63, 64..95, 96..127}; the gemm ORs the 4 partials.
#define FLAG_HALFWORDS 512
#define SCAN_JOBS (FLAG_HALFWORDS * 4)   // 2048 quarter-region scan jobs

typedef __attribute__((ext_vector_type(8))) __bf16 bf16x8;
typedef __attribute__((ext_vector_type(8))) unsigned short u16x8;
typedef __attribute__((ext_vector_type(4))) float f32x4;

// ---------- quantization: nearest of {0,±1,±.5,±.333333,±.2,±.142857,±.090909,±.076923} ----------
// Tie-break matches the reference's first-min LUT scan:
//   boundary to 0 (index 0 first) -> strict >; between nonzero magnitudes -> >=
__device__ __forceinline__ float quantize_ws(float ws, float scale) {
    float a  = fabsf(ws);
    float v  = 0.0f;
    v = (a >  0.0384615f) ? 0.076923f : v;
    v = (a >= 0.0839160f) ? 0.090909f : v;
    v = (a >= 0.1168830f) ? 0.142857f : v;
    v = (a >= 0.1714285f) ? 0.2f      : v;
    v = (a >= 0.2666665f) ? 0.333333f : v;
    v = (a >= 0.4166665f) ? 0.5f      : v;
    v = (a >= 0.75f)      ? 1.0f      : v;
    v = copysignf(v, ws);
    return v * scale;
}

__device__ __forceinline__ unsigned short to_bf16(float f) {
    unsigned int u = __float_as_uint(f);
    u += 0x7FFFu + ((u >> 16) & 1u);   // RNE
    return (unsigned short)(u >> 16);
}

// ---------- pass 1: scan W -> partial flags (no atomics/memset) + zero-fill C ----------
// Duty A: 2048 jobs; job = (halfword sb, row-quarter p). Each block scans a
// 32x512 region of W (64 KiB, nontemporal float4), wave-OR + LDS-OR reduce,
// single ushort store to its own slot -> no atomics. 8 blocks/CU occupancy.
// Duty B: 4 jobs per C tile (32 rows x 128 cols each), nontemporal zero-fill.
// Read (128 MiB) and write (32 MiB) streams overlap in one dispatch; nt
// hints avoid LLC allocation for touch-once data.
__global__ __launch_bounds__(256) void scan_fill_kernel(
        const float* __restrict__ W,
        const float* __restrict__ scale_p,
        unsigned short* __restrict__ flags_h,   // [4][512]
        float* __restrict__ C, int M) {
    __shared__ unsigned int red[4];
    const int tid = threadIdx.x;
    const int b   = blockIdx.x;
    const int nwg = gridDim.x;
    const float th = 0.0384615f * fabsf(scale_p[0]);
    const f32x4* W4 = (const f32x4*)W;

    // --- duty A: partial flag halfwords ---
    for (int job = b; job < SCAN_JOBS; job += nwg) {
        int sb    = job >> 2;          // halfword index
        int p     = job & 3;           // row quarter
        int ntile = sb >> 3;           // W row tile (N dim)
        int kh    = sb & 7;            // col half-word
        unsigned int mask = 0u;
        const size_t base = (size_t)(ntile * 128 + p * 32) * (K_DIM / 4) + kh * 128;
        // 32 rows x 128 float4; consecutive tid -> consecutive float4 (coalesced)
#pragma unroll 4
        for (int e = tid; e < 32 * 128; e += 256) {
            int row = e >> 7;
            int c4  = e & 127;
            f32x4 w = __builtin_nontemporal_load(&W4[base + (size_t)row * (K_DIM / 4) + c4]);
            float amax = fmaxf(fmaxf(fabsf(w[0]), fabsf(w[1])), fmaxf(fabsf(w[2]), fabsf(w[3])));
            if (amax > th) mask |= 1u << (c4 >> 3);    // bit = kchunk within halfword
        }
#pragma unroll
        for (int off = 32; off; off >>= 1) mask |= __shfl_down(mask, off, 64);
        if ((tid & 63) == 0) red[tid >> 6] = mask;
        __syncthreads();
        if (tid == 0)
            flags_h[p * FLAG_HALFWORDS + sb] =
                (unsigned short)(red[0] | red[1] | red[2] | red[3]);
        __syncthreads();               // red[] reuse safety when grid-striding
    }

    // --- duty B: zero C (quarter-tiles of 32 rows x 128 cols) ---
    const int cjobs = (M / 128) * NTILES * 4;
    const f32x4 zz = {0.f, 0.f, 0.f, 0.f};
    for (int job = b; job < cjobs; job += nwg) {
        int tile  = job >> 2;
        int sub   = job & 3;
        int mtile = tile >> 6;
        int ntile = tile & 63;
        float* Cb = C + (size_t)(mtile * 128 + sub * 32) * N_DIM + ntile * 128;
#pragma unroll 4
        for (int g = tid; g < 32 * 32; g += 256) {     // 32 rows x 32 float4
            int r = g >> 5, c = g & 31;
            __builtin_nontemporal_store(zz, (f32x4*)(Cb + (size_t)r * N_DIM) + c);
        }
    }
}

// ---------- pass 2: sparse-aware GEMM, C = x @ quant(W)^T, staging from fp32 ----------
// 128x128 tile, BK=32, 2x2 waves, 4x4 frags, 64 B LDS rows. Per-block early
// exit: OR of 4 partial flag uint4s zero -> return (C tile zeroed by pass 1).
// Nonzero chunks: stage A from fp32 x (bf16-convert) and B from fp32 W
// (quantize+convert) on the fly. Skipping a zero chunk is BIT-EXACT: every
// skipped term is acc += a*0, and x+0.0 == x.
__global__ __launch_bounds__(256) void gemm_bt_bf16(
        const float* __restrict__ X,            // [M][K] fp32
        const float* __restrict__ Wf,           // [N][K] fp32
        const float* __restrict__ scale_p,
        const unsigned int* __restrict__ flags, // uint view of flags_h [4][512]
        float* __restrict__ C, int M) {
    __shared__ unsigned short sA[128 * 32];     // row-major [m][k], 64 B rows
    __shared__ unsigned short sB[128 * 32];

    const int tid  = threadIdx.x;
    const int ntile = blockIdx.x & 63;          // N/128 = 64
    const int mtile = blockIdx.x >> 6;
    const int m0 = mtile * 128;
    const int n0 = ntile * 128;

    const uint4* fp = (const uint4*)flags;      // 4 arrays of 64 uint4 each
    const uint4 p0 = fp[0 * 64 + ntile];
    const uint4 p1 = fp[1 * 64 + ntile];
    const uint4 p2 = fp[2 * 64 + ntile];
    const uint4 p3 = fp[3 * 64 + ntile];
    const unsigned int f0 = p0.x | p1.x | p2.x | p3.x;
    const unsigned int f1 = p0.y | p1.y | p2.y | p3.y;
    const unsigned int f2 = p0.z | p1.z | p2.z | p3.z;
    const unsigned int f3 = p0.w | p1.w | p2.w | p3.w;

    if ((f0 | f1 | f2 | f3) == 0u) return;      // C tile already zero-filled

    const float s   = scale_p[0];
    const float inv = 1.0f / s;

    const int w    = tid >> 6;
    const int lane = tid & 63;
    const int quad = lane >> 4;
    const int l16  = lane & 15;
    const int wm   = w >> 1;                    // 2x2 wave grid
    const int wn   = w & 1;

    f32x4 acc[4][4];
    const f32x4 z = {0.f, 0.f, 0.f, 0.f};
#pragma unroll
    for (int i = 0; i < 4; ++i)
#pragma unroll
        for (int j = 0; j < 4; ++j) acc[i][j] = z;

    char* sAb = (char*)sA;
    char* sBb = (char*)sB;

    for (int k0 = 0; k0 < K_DIM; k0 += 32) {
        int ch = k0 >> 5;
        unsigned int word = (ch < 64) ? ((ch < 32) ? f0 : f1)
                                      : ((ch < 96) ? f2 : f3);
        if (!((word >> (ch & 31)) & 1u)) continue;   // block-uniform skip

        // stage 128x32: 512 groups of 8 elems; group g -> row g>>2, seg g&3.
        // Lanes 0..3 cover one row's 128 B contiguous fp32 -> coalesced.
#pragma unroll
        for (int p = 0; p < 2; ++p) {
            int g   = p * 256 + tid;
            int row = g >> 2;
            int seg = g & 3;
            const float* xa = X  + (size_t)(m0 + row) * K_DIM + k0 + seg * 8;
            const float* wb = Wf + (size_t)(n0 + row) * K_DIM + k0 + seg * 8;
            float4 a0 = *(const float4*)xa;
            float4 a1 = *(const float4*)(xa + 4);
            float4 b0 = *(const float4*)wb;
            float4 b1 = *(const float4*)(wb + 4);
            u16x8 qa, qb;
            qa[0] = to_bf16(a0.x); qa[1] = to_bf16(a0.y);
            qa[2] = to_bf16(a0.z); qa[3] = to_bf16(a0.w);
            qa[4] = to_bf16(a1.x); qa[5] = to_bf16(a1.y);
            qa[6] = to_bf16(a1.z); qa[7] = to_bf16(a1.w);
            qb[0] = to_bf16(quantize_ws(b0.x * inv, s));
            qb[1] = to_bf16(quantize_ws(b0.y * inv, s));
            qb[2] = to_bf16(quantize_ws(b0.z * inv, s));
            qb[3] = to_bf16(quantize_ws(b0.w * inv, s));
            qb[4] = to_bf16(quantize_ws(b1.x * inv, s));
            qb[5] = to_bf16(quantize_ws(b1.y * inv, s));
            qb[6] = to_bf16(quantize_ws(b1.z * inv, s));
            qb[7] = to_bf16(quantize_ws(b1.w * inv, s));
            *(u16x8*)(sAb + row * 64 + seg * 16) = qa;
            *(u16x8*)(sBb + row * 64 + seg * 16) = qb;
        }
        __syncthreads();

        bf16x8 af[4], bf[4];
#pragma unroll
        for (int i = 0; i < 4; ++i) {
            af[i] = *(const bf16x8*)(sAb + ((size_t)(wm * 64 + i * 16 + l16) * 32 + quad * 8) * 2);
            bf[i] = *(const bf16x8*)(sBb + ((size_t)(wn * 64 + i * 16 + l16) * 32 + quad * 8) * 2);
        }
#pragma unroll
        for (int mi = 0; mi < 4; ++mi)
#pragma unroll
            for (int ni = 0; ni < 4; ++ni)
                acc[mi][ni] = __builtin_amdgcn_mfma_f32_16x16x32_bf16(af[mi], bf[ni], acc[mi][ni], 0, 0, 0);
        __syncthreads();
    }

    // epilogue: D row = m (quad*4+reg), col = n (lane&15)  [verified mapping, m89/m91]
#pragma unroll
    for (int mi = 0; mi < 4; ++mi) {
#pragma unroll
        for (int ni = 0; ni < 4; ++ni) {
            int row = m0 + wm * 64 + mi * 16 + quad * 4;
            int col = n0 + wn * 64 + ni * 16 + l16;
#pragma unroll
            for (int r = 0; r < 4; ++r)
                C[(size_t)(row + r) * N_DIM + col] = acc[mi][ni][r];
        }
    }
}

// ---------- fallback (no usable workspace / odd M): fp32 tiled GEMM, quantize in staging ----------
__global__ __launch_bounds__(256) void gemm_fp32_fb(const float* __restrict__ A,
                                                    const float* __restrict__ B,
                                                    const float* __restrict__ scale_p,
                                                    float* __restrict__ C, int M) {
    __shared__ float sA[64][17];
    __shared__ float sB[64][17];
    const float s   = scale_p[0];
    const float inv = 1.0f / s;
    int tid = threadIdx.x;
    int tx = tid & 15, ty = tid >> 4;
    int n0 = (blockIdx.x & 127) * 64;          // N/64 = 128
    int m0 = (blockIdx.x >> 7) * 64;
    float acc[4][4] = {};
    for (int k0 = 0; k0 < K_DIM; k0 += 16) {
#pragma unroll
        for (int i = 0; i < 4; ++i) {
            int e = tid + i * 256;
            int r = e >> 4, c = e & 15;
            sA[r][c] = A[(size_t)(m0 + r) * K_DIM + k0 + c];
            sB[r][c] = quantize_ws(B[(size_t)(n0 + r) * K_DIM + k0 + c] * inv, s);
        }
        __syncthreads();
#pragma unroll
        for (int kk = 0; kk < 16; ++kk) {
            float a[4], b[4];
#pragma unroll
            for (int i = 0; i < 4; ++i) { a[i] = sA[ty * 4 + i][kk]; b[i] = sB[tx * 4 + i][kk]; }
#pragma unroll
            for (int i = 0; i < 4; ++i)
#pragma unroll
                for (int j = 0; j < 4; ++j) acc[i][j] += a[i] * b[j];
        }
        __syncthreads();
    }
#pragma unroll
    for (int i = 0; i < 4; ++i)
#pragma unroll
        for (int j = 0; j < 4; ++j)
            C[(size_t)(m0 + ty * 4 + i) * N_DIM + n0 + tx * 4 + j] = acc[i][j];
}

extern "C" void kernel_launch(void* const* d_in, const int* in_sizes, int n_in,
                              void* d_out, int out_size, void* d_ws, size_t ws_size,
                              hipStream_t stream) {
    const float* x     = (const float*)d_in[0];
    const float* W     = (const float*)d_in[1];
    const float* scale = (const float*)d_in[2];
    float* out = (float*)d_out;

    const int M = in_sizes[0] / K_DIM;                       // 1024
    const size_t fl_bytes = (size_t)4 * FLAG_HALFWORDS * sizeof(unsigned short);  // 4 KiB

    if (ws_size >= fl_bytes && (M % 128) == 0) {
        unsigned short* flags_h = (unsigned short*)d_ws;
        int cjobs = (M / 128) * NTILES * 4;
        int grid1 = (cjobs > SCAN_JOBS) ? cjobs : SCAN_JOBS;
        hipLaunchKernelGGL(scan_fill_kernel, dim3(grid1), dim3(256), 0, stream,
                           W, scale, flags_h, out, M);
        hipLaunchKernelGGL(gemm_bt_bf16, dim3((M / 128) * NTILES), dim3(256), 0, stream,
                           x, W, scale, (const unsigned int*)flags_h, out, M);
    } else {
        hipLaunchKernelGGL(gemm_fp32_fb, dim3((M / 64) * (N_DIM / 64)), dim3(256), 0, stream,
                           x, W, scale, out, M);
    }
}

// Round 5
// 202.248 us; speedup vs baseline: 1.0327x; 1.0033x over previous
//
#include <hip/hip_runtime.h>
#include <hip/hip_bf16.h>
#include <stdint.h>

#define K_DIM 4096
#define N_DIM 8192
#define NTILES (N_DIM / 128)          // 64 B-row tiles
// flags4: [NTILES][32] uint4 partial masks. Partial p of ntile covers W rows
// ntile*128 + p*4 .. +3 (one scan job = 4 contiguous rows = 64 KiB).
// uint4 word j, bit i  <=>  kchunk j*32+i (BK=32 cols) has a nonzero quant.
// Each slot is written by exactly one block -> no atomics, no memset.
#define SCAN_JOBS 2048                // 8192 rows / 4
#define FLAG_BYTES (NTILES * 32 * sizeof(uint4))   // 32 KiB

typedef __attribute__((ext_vector_type(8))) __bf16 bf16x8;
typedef __attribute__((ext_vector_type(8))) unsigned short u16x8;
typedef __attribute__((ext_vector_type(4))) float f32x4;

// ---------- quantization: nearest of {0,±1,±.5,±.333333,±.2,±.142857,±.090909,±.076923} ----------
// Tie-break matches the reference's first-min LUT scan:
//   boundary to 0 (index 0 first) -> strict >; between nonzero magnitudes -> >=
__device__ __forceinline__ float quantize_ws(float ws, float scale) {
    float a  = fabsf(ws);
    float v  = 0.0f;
    v = (a >  0.0384615f) ? 0.076923f : v;
    v = (a >= 0.0839160f) ? 0.090909f : v;
    v = (a >= 0.1168830f) ? 0.142857f : v;
    v = (a >= 0.1714285f) ? 0.2f      : v;
    v = (a >= 0.2666665f) ? 0.333333f : v;
    v = (a >= 0.4166665f) ? 0.5f      : v;
    v = (a >= 0.75f)      ? 1.0f      : v;
    v = copysignf(v, ws);
    return v * scale;
}

__device__ __forceinline__ unsigned short to_bf16(float f) {
    unsigned int u = __float_as_uint(f);
    u += 0x7FFFu + ((u >> 16) & 1u);   // RNE
    return (unsigned short)(u >> 16);
}

// ---------- pass 1: zero-fill C + scan W -> partial flags ----------
// Duty B first (fire-and-forget nt stores drain under the read stream), then
// duty A: each block reads a CONTIGUOUS 64 KiB slab (4 W rows). For thread
// tid, iter k: flag word = k&3, bit = tid>>3 (both compile-time after unroll)
// -> 16 fully-independent nt loads + a handful of VALU ops per thread.
__global__ __launch_bounds__(256) void scan_fill_kernel(
        const float* __restrict__ W,
        const float* __restrict__ scale_p,
        uint4* __restrict__ flags4,     // [NTILES][32]
        float* __restrict__ C, int M) {
    __shared__ unsigned int red[4][4];  // [wave][word]
    const int tid = threadIdx.x;
    const int b   = blockIdx.x;
    const int nwg = gridDim.x;
    const float th = 0.0384615f * fabsf(scale_p[0]);
    const f32x4* W4 = (const f32x4*)W;

    // --- duty B: zero C (quarter-tiles of 32 rows x 128 cols) ---
    const int cjobs = (M / 128) * NTILES * 4;
    const f32x4 zz = {0.f, 0.f, 0.f, 0.f};
    for (int job = b; job < cjobs; job += nwg) {
        int tile  = job >> 2;
        int sub   = job & 3;
        int mtile = tile >> 6;
        int ntile = tile & 63;
        float* Cb = C + (size_t)(mtile * 128 + sub * 32) * N_DIM + ntile * 128;
#pragma unroll 4
        for (int g = tid; g < 32 * 32; g += 256) {     // 32 rows x 32 float4
            int r = g >> 5, c = g & 31;
            __builtin_nontemporal_store(zz, (f32x4*)(Cb + (size_t)r * N_DIM) + c);
        }
    }

    // --- duty A: scan 4-row slabs ---
    for (int job = b; job < SCAN_JOBS; job += nwg) {
        const size_t base = (size_t)job * 4 * (K_DIM / 4);   // float4 index of row job*4
        bool big[4] = {false, false, false, false};
#pragma unroll
        for (int k = 0; k < 16; ++k) {
            f32x4 w = __builtin_nontemporal_load(&W4[base + tid + k * 256]);
            float amax = fmaxf(fmaxf(fabsf(w[0]), fabsf(w[1])), fmaxf(fabsf(w[2]), fabsf(w[3])));
            big[k & 3] = big[k & 3] | (amax > th);
            // word (k&3): c4 = (tid+256k)&1023 -> c4>>8 == k&3; bit: (c4>>3)&31 == tid>>3
        }
        const unsigned int bit = 1u << (tid >> 3);
        unsigned int mw[4];
#pragma unroll
        for (int j = 0; j < 4; ++j) mw[j] = big[j] ? bit : 0u;
#pragma unroll
        for (int j = 0; j < 4; ++j) {
            unsigned int m = mw[j];
#pragma unroll
            for (int off = 32; off; off >>= 1) m |= __shfl_down(m, off, 64);
            if ((tid & 63) == 0) red[tid >> 6][j] = m;
        }
        __syncthreads();
        if (tid == 0) {
            uint4 o;
            o.x = red[0][0] | red[1][0] | red[2][0] | red[3][0];
            o.y = red[0][1] | red[1][1] | red[2][1] | red[3][1];
            o.z = red[0][2] | red[1][2] | red[2][2] | red[3][2];
            o.w = red[0][3] | red[1][3] | red[2][3] | red[3][3];
            flags4[(job >> 5) * 32 + (job & 31)] = o;    // ntile = job>>5, p = job&31
        }
        __syncthreads();               // red[] reuse safety when grid-striding
    }
}

// ---------- pass 2: sparse-aware GEMM, C = x @ quant(W)^T, staging from fp32 ----------
// 128x128 tile, BK=32, 2x2 waves, 4x4 frags, 64 B LDS rows. Per-block early
// exit: OR of 32 partial uint4s zero -> return (C tile zeroed by pass 1).
// Nonzero chunks: stage A from fp32 x (bf16-convert) and B from fp32 W
// (quantize+convert) on the fly. Skipping a zero chunk is BIT-EXACT: every
// skipped term is acc += a*0, and x+0.0 == x.
__global__ __launch_bounds__(256) void gemm_bt_bf16(
        const float* __restrict__ X,            // [M][K] fp32
        const float* __restrict__ Wf,           // [N][K] fp32
        const float* __restrict__ scale_p,
        const uint4* __restrict__ flags4,       // [NTILES][32]
        float* __restrict__ C, int M) {
    __shared__ unsigned short sA[128 * 32];     // row-major [m][k], 64 B rows
    __shared__ unsigned short sB[128 * 32];

    const int tid  = threadIdx.x;
    const int ntile = blockIdx.x & 63;          // N/128 = 64
    const int mtile = blockIdx.x >> 6;
    const int m0 = mtile * 128;
    const int n0 = ntile * 128;

    unsigned int f0 = 0u, f1 = 0u, f2 = 0u, f3 = 0u;
    const uint4* fp = flags4 + ntile * 32;
#pragma unroll 8
    for (int i = 0; i < 32; ++i) {              // uniform -> scalar loads
        uint4 v = fp[i];
        f0 |= v.x; f1 |= v.y; f2 |= v.z; f3 |= v.w;
    }

    if ((f0 | f1 | f2 | f3) == 0u) return;      // C tile already zero-filled

    const float s   = scale_p[0];
    const float inv = 1.0f / s;

    const int w    = tid >> 6;
    const int lane = tid & 63;
    const int quad = lane >> 4;
    const int l16  = lane & 15;
    const int wm   = w >> 1;                    // 2x2 wave grid
    const int wn   = w & 1;

    f32x4 acc[4][4];
    const f32x4 z = {0.f, 0.f, 0.f, 0.f};
#pragma unroll
    for (int i = 0; i < 4; ++i)
#pragma unroll
        for (int j = 0; j < 4; ++j) acc[i][j] = z;

    char* sAb = (char*)sA;
    char* sBb = (char*)sB;

    for (int k0 = 0; k0 < K_DIM; k0 += 32) {
        int ch = k0 >> 5;
        unsigned int word = (ch < 64) ? ((ch < 32) ? f0 : f1)
                                      : ((ch < 96) ? f2 : f3);
        if (!((word >> (ch & 31)) & 1u)) continue;   // block-uniform skip

        // stage 128x32: 512 groups of 8 elems; group g -> row g>>2, seg g&3.
        // Lanes 0..3 cover one row's 128 B contiguous fp32 -> coalesced.
#pragma unroll
        for (int p = 0; p < 2; ++p) {
            int g   = p * 256 + tid;
            int row = g >> 2;
            int seg = g & 3;
            const float* xa = X  + (size_t)(m0 + row) * K_DIM + k0 + seg * 8;
            const float* wb = Wf + (size_t)(n0 + row) * K_DIM + k0 + seg * 8;
            float4 a0 = *(const float4*)xa;
            float4 a1 = *(const float4*)(xa + 4);
            float4 b0 = *(const float4*)wb;
            float4 b1 = *(const float4*)(wb + 4);
            u16x8 qa, qb;
            qa[0] = to_bf16(a0.x); qa[1] = to_bf16(a0.y);
            qa[2] = to_bf16(a0.z); qa[3] = to_bf16(a0.w);
            qa[4] = to_bf16(a1.x); qa[5] = to_bf16(a1.y);
            qa[6] = to_bf16(a1.z); qa[7] = to_bf16(a1.w);
            qb[0] = to_bf16(quantize_ws(b0.x * inv, s));
            qb[1] = to_bf16(quantize_ws(b0.y * inv, s));
            qb[2] = to_bf16(quantize_ws(b0.z * inv, s));
            qb[3] = to_bf16(quantize_ws(b0.w * inv, s));
            qb[4] = to_bf16(quantize_ws(b1.x * inv, s));
            qb[5] = to_bf16(quantize_ws(b1.y * inv, s));
            qb[6] = to_bf16(quantize_ws(b1.z * inv, s));
            qb[7] = to_bf16(quantize_ws(b1.w * inv, s));
            *(u16x8*)(sAb + row * 64 + seg * 16) = qa;
            *(u16x8*)(sBb + row * 64 + seg * 16) = qb;
        }
        __syncthreads();

        bf16x8 af[4], bf[4];
#pragma unroll
        for (int i = 0; i < 4; ++i) {
            af[i] = *(const bf16x8*)(sAb + ((size_t)(wm * 64 + i * 16 + l16) * 32 + quad * 8) * 2);
            bf[i] = *(const bf16x8*)(sBb + ((size_t)(wn * 64 + i * 16 + l16) * 32 + quad * 8) * 2);
        }
#pragma unroll
        for (int mi = 0; mi < 4; ++mi)
#pragma unroll
            for (int ni = 0; ni < 4; ++ni)
                acc[mi][ni] = __builtin_amdgcn_mfma_f32_16x16x32_bf16(af[mi], bf[ni], acc[mi][ni], 0, 0, 0);
        __syncthreads();
    }

    // epilogue: D row = m (quad*4+reg), col = n (lane&15)  [verified mapping, m89/m91]
#pragma unroll
    for (int mi = 0; mi < 4; ++mi) {
#pragma unroll
        for (int ni = 0; ni < 4; ++ni) {
            int row = m0 + wm * 64 + mi * 16 + quad * 4;
            int col = n0 + wn * 64 + ni * 16 + l16;
#pragma unroll
            for (int r = 0; r < 4; ++r)
                C[(size_t)(row + r) * N_DIM + col] = acc[mi][ni][r];
        }
    }
}

// ---------- fallback (no usable workspace / odd M): fp32 tiled GEMM, quantize in staging ----------
__global__ __launch_bounds__(256) void gemm_fp32_fb(const float* __restrict__ A,
                                                    const float* __restrict__ B,
                                                    const float* __restrict__ scale_p,
                                                    float* __restrict__ C, int M) {
    __shared__ float sA[64][17];
    __shared__ float sB[64][17];
    const float s   = scale_p[0];
    const float inv = 1.0f / s;
    int tid = threadIdx.x;
    int tx = tid & 15, ty = tid >> 4;
    int n0 = (blockIdx.x & 127) * 64;          // N/64 = 128
    int m0 = (blockIdx.x >> 7) * 64;
    float acc[4][4] = {};
    for (int k0 = 0; k0 < K_DIM; k0 += 16) {
#pragma unroll
        for (int i = 0; i < 4; ++i) {
            int e = tid + i * 256;
            int r = e >> 4, c = e & 15;
            sA[r][c] = A[(size_t)(m0 + r) * K_DIM + k0 + c];
            sB[r][c] = quantize_ws(B[(size_t)(n0 + r) * K_DIM + k0 + c] * inv, s);
        }
        __syncthreads();
#pragma unroll
        for (int kk = 0; kk < 16; ++kk) {
            float a[4], b[4];
#pragma unroll
            for (int i = 0; i < 4; ++i) { a[i] = sA[ty * 4 + i][kk]; b[i] = sB[tx * 4 + i][kk]; }
#pragma unroll
            for (int i = 0; i < 4; ++i)
#pragma unroll
                for (int j = 0; j < 4; ++j) acc[i][j] += a[i] * b[j];
        }
        __syncthreads();
    }
#pragma unroll
    for (int i = 0; i < 4; ++i)
#pragma unroll
        for (int j = 0; j < 4; ++j)
            C[(size_t)(m0 + ty * 4 + i) * N_DIM + n0 + tx * 4 + j] = acc[i][j];
}

extern "C" void kernel_launch(void* const* d_in, const int* in_sizes, int n_in,
                              void* d_out, int out_size, void* d_ws, size_t ws_size,
                              hipStream_t stream) {
    const float* x     = (const float*)d_in[0];
    const float* W     = (const float*)d_in[1];
    const float* scale = (const float*)d_in[2];
    float* out = (float*)d_out;

    const int M = in_sizes[0] / K_DIM;                       // 1024

    if (ws_size >= FLAG_BYTES && (M % 128) == 0) {
        uint4* flags4 = (uint4*)d_ws;
        int cjobs = (M / 128) * NTILES * 4;
        int grid1 = (cjobs > SCAN_JOBS) ? cjobs : SCAN_JOBS;
        hipLaunchKernelGGL(scan_fill_kernel, dim3(grid1), dim3(256), 0, stream,
                           W, scale, flags4, out, M);
        hipLaunchKernelGGL(gemm_bt_bf16, dim3((M / 128) * NTILES), dim3(256), 0, stream,
                           x, W, scale, flags4, out, M);
    } else {
        hipLaunchKernelGGL(gemm_fp32_fb, dim3((M / 64) * (N_DIM / 64)), dim3(256), 0, stream,
                           x, W, scale, out, M);
    }
}